// Round 4
// baseline (109.182 us; speedup 1.0000x reference)
//
#include <hip/hip_runtime.h>

// ElementalGTO fingerprint kernel for MI355X (gfx950), round 4.
// B=32, N=128, 4 species, 20 gaussians, LMAX=2 -> 10 ang comps, FP_SIZE=600.
//
// Pair channels are cross terms: fpp[p] = sum_a 2*w_a*t[pi][a][g]*t[pj][a][g],
// so only per-species t[s][a][g] is accumulated.
//
// R4 (occupancy attack): no coord LDS (own coords from global, atom-n coords
// wave-uniform scalar loads); bf16-packed ang/rad tables (threshold 123.5 is
// ~2% of output max -> bf16's ~0.3% is safe); single-copy fp32 st via
// ds_add_f32 atomics; 3 barriers. LDS 23.4 KB -> 11.2 KB => 14 blocks/CU.
// Phase 2: 50 lanes/wave, 2 ang x 2 gauss per lane, species separation via
// prefix snapshots at wave-uniform sorted-bucket boundaries. Radial gaussians
// via 2-exp geometric recurrence instead of 20 __expf.

#define NATOM 128

__device__ const float d_wA[10]   = {1.f,1.f,1.f,1.f,1.f,2.f,1.f,2.f,2.f,1.f};
__device__ const int   d_abase[3] = {0, 1, 4};
__device__ const int   d_acnt[3]  = {1, 3, 6};
__device__ const int   d_PI[6]    = {0,0,0,1,1,2};
__device__ const int   d_PJ[6]    = {1,2,3,2,3,3};

__device__ __forceinline__ unsigned pack2_bf16(float lo, float hi) {
    // round-half-up on magnitude; values are finite, error <= 0.5 ulp + tiny bias
    unsigned ul = __float_as_uint(lo) + 0x8000u;
    unsigned uh = __float_as_uint(hi) + 0x8000u;
    return (ul >> 16) | (uh & 0xffff0000u);
}

__global__ __launch_bounds__(128)
void egto_kernel(const float* __restrict__ coords,
                 const int*   __restrict__ charges,
                 const int*   __restrict__ natoms,
                 float*       __restrict__ out)
{
    __shared__ int      wcnt[2][5];
    __shared__ unsigned sang[NATOM * 5];    // bf16x2 [slot][apair], row 20 B
    __shared__ unsigned srad[NATOM * 11];   // bf16x2 [slot][gpair], row 44 B (col 10 pad)
    __shared__ float    st[800];            // [s][a][g] fp32, single copy

    const int bid  = blockIdx.x;
    const int b    = bid >> 7;
    const int n    = bid & 127;
    const int t    = threadIdx.x;
    const int wid  = t >> 6;
    const int lane = t & 63;

    const float* cb = coords + (size_t)b * NATOM * 3;
    // own coords (per-lane) + atom n coords (wave-uniform -> scalar loads)
    const float cx = cb[t * 3 + 0];
    const float cy = cb[t * 3 + 1];
    const float cz = cb[t * 3 + 2];
    const float xn = cb[n * 3 + 0];
    const float yn = cb[n * 3 + 1];
    const float zn = cb[n * 3 + 2];
    const int ch = charges[b * NATOM + t];
    const int sp = (ch == 1) ? 0 : (ch == 6) ? 1 : (ch == 7) ? 2 : 3;
    const int natom = natoms[b];

    // zero the accumulator tile (ds_add target)
    for (int i = t; i < 800; i += 128) st[i] = 0.f;

    const float dx = xn - cx;
    const float dy = yn - cy;
    const float dz = zn - cz;
    const float d2 = dx * dx + dy * dy + dz * dz;
    const bool  valid = (d2 < 36.0f) && (t != n) && (t < natom);
    const int   key = valid ? sp : 4;          // bucket 4 = discard

    // ---- 5-bucket ballot ranking (per wave) ----
    const unsigned long long m0 = __ballot(key == 0);
    const unsigned long long m1 = __ballot(key == 1);
    const unsigned long long m2 = __ballot(key == 2);
    const unsigned long long m3 = __ballot(key == 3);
    const unsigned long long below = (1ull << lane) - 1ull;
    const unsigned long long msel =
        (key == 0) ? m0 : (key == 1) ? m1 : (key == 2) ? m2 : (key == 3) ? m3
                    : ~(m0 | m1 | m2 | m3);
    const int rank = __popcll(msel & below);
    if (lane == 0) {
        const int n0 = __popcll(m0), n1 = __popcll(m1), n2 = __popcll(m2), n3 = __popcll(m3);
        wcnt[wid][0] = n0; wcnt[wid][1] = n1; wcnt[wid][2] = n2; wcnt[wid][3] = n3;
        wcnt[wid][4] = 64 - n0 - n1 - n2 - n3;
    }
    __syncthreads();   // barrier 1: wcnt + st-zero visible

    const int c0 = wcnt[0][0] + wcnt[1][0];
    const int c1 = wcnt[0][1] + wcnt[1][1];
    const int c2 = wcnt[0][2] + wcnt[1][2];
    const int c3 = wcnt[0][3] + wcnt[1][3];
    const int B1 = c0, B2 = B1 + c1, B3 = B2 + c2, B4 = B3 + c3;  // B4 = valid count
    const int bstart = (key == 0) ? 0 : (key == 1) ? B1 : (key == 2) ? B2
                     : (key == 3) ? B3 : B4;
    const int slot = bstart + (wid ? wcnt[0][key] : 0) + rank;
    const int cap_r = (B4 + 7) & ~7;

    // ---- phase 1: per-neighbor bf16 tables at permuted slot ----
    if (valid) {
        const float dist = sqrtf(d2);
        const float cutoff = 0.5f * (__cosf(dist * 0.52359877559829887f) + 1.0f);
        const float cm = 0.79788456080286536f * cutoff;   // sqrt(2/pi)*cutoff
        const float invd = 1.0f / dist;
        const float i2 = invd * invd;
        const float i3 = i2 * invd;
        const float i4 = i2 * i2;
        unsigned* ap = &sang[slot * 5];
        ap[0] = pack2_bf16(i2,           i3 * dx);
        ap[1] = pack2_bf16(i3 * dy,      i3 * dz);
        ap[2] = pack2_bf16(i4 * dx * dx, i4 * dx * dy);
        ap[3] = pack2_bf16(i4 * dy * dy, i4 * dx * dz);
        ap[4] = pack2_bf16(i4 * dy * dz, i4 * dz * dz);
        // radial gaussians by geometric recurrence:
        // rad_g = cm*exp(-2*u_g^2), u_g = dist-0.3(g+1)
        // rad_{g+1} = rad_g * exp(1.2*u_g - 0.18); ratio *= exp(-0.36)
        const float u0 = dist - 0.3f;
        float val   = cm * __expf(-2.0f * u0 * u0);
        float ratio = __expf(1.2f * u0 - 0.18f);
        const float cmul = 0.697676326071031f;            // exp(-0.36)
        unsigned* rp = &srad[slot * 11];
#pragma unroll
        for (int j = 0; j < 10; ++j) {
            const float r0 = val;
            val *= ratio; ratio *= cmul;
            const float r1 = val;
            val *= ratio; ratio *= cmul;
            rp[j] = pack2_bf16(r0, r1);
        }
    } else if (slot < cap_r) {
        unsigned* ap = &sang[slot * 5];
        unsigned* rp = &srad[slot * 11];
#pragma unroll
        for (int k = 0; k < 5; ++k) ap[k] = 0u;
#pragma unroll
        for (int j = 0; j < 10; ++j) rp[j] = 0u;
    }
    __syncthreads();   // barrier 2: tables ready

    // ---- phase 2: prefix accumulation with boundary snapshots ----
    if (lane < 50) {
        const int apair = lane / 10;       // a in {2*apair, 2*apair+1}
        const int gp    = lane - 10 * apair; // g in {2*gp, 2*gp+1}
        const unsigned* angd = &sang[apair];
        const unsigned* radd = &srad[gp];

        // last m in this wave's parity sequence strictly below each boundary
        int t1 = B1 - 1; t1 -= (t1 - wid) & 1;
        int t2 = B2 - 1; t2 -= (t2 - wid) & 1;
        int t3 = B3 - 1; t3 -= (t3 - wid) & 1;

        float4 acc = {0,0,0,0};
        float4 s1  = {0,0,0,0}, s2 = {0,0,0,0}, s3 = {0,0,0,0};

        auto body = [&](int m) {
            const unsigned av = angd[m * 5];
            const unsigned rv = radd[m * 11];
            const float a0 = __uint_as_float(av << 16);
            const float a1 = __uint_as_float(av & 0xffff0000u);
            const float r0 = __uint_as_float(rv << 16);
            const float r1 = __uint_as_float(rv & 0xffff0000u);
            acc.x = fmaf(a0, r0, acc.x);
            acc.y = fmaf(a0, r1, acc.y);
            acc.z = fmaf(a1, r0, acc.z);
            acc.w = fmaf(a1, r1, acc.w);
        };

        for (int i = 0; i < cap_r; i += 8) {
            const bool bhit = ((unsigned)(t1 - i) < 8u) |
                              ((unsigned)(t2 - i) < 8u) |
                              ((unsigned)(t3 - i) < 8u);
            if (!bhit) {
#pragma unroll
                for (int u = 0; u < 4; ++u) body(i + wid + 2 * u);
            } else {
#pragma unroll
                for (int u = 0; u < 4; ++u) {
                    const int m = i + wid + 2 * u;
                    body(m);
                    if (m == t1) s1 = acc;
                    if (m == t2) s2 = acc;
                    if (m == t3) s3 = acc;
                }
            }
        }

        // segment sums from prefix snapshots -> atomic add into shared st
        const int base = apair * 40 + gp * 2;   // (2*apair)*20 + 2*gp
        float4 v;
        v = s1;
        atomicAdd(&st[0 * 200 + base +  0], v.x);
        atomicAdd(&st[0 * 200 + base +  1], v.y);
        atomicAdd(&st[0 * 200 + base + 20], v.z);
        atomicAdd(&st[0 * 200 + base + 21], v.w);
        v = make_float4(s2.x - s1.x, s2.y - s1.y, s2.z - s1.z, s2.w - s1.w);
        atomicAdd(&st[1 * 200 + base +  0], v.x);
        atomicAdd(&st[1 * 200 + base +  1], v.y);
        atomicAdd(&st[1 * 200 + base + 20], v.z);
        atomicAdd(&st[1 * 200 + base + 21], v.w);
        v = make_float4(s3.x - s2.x, s3.y - s2.y, s3.z - s2.z, s3.w - s2.w);
        atomicAdd(&st[2 * 200 + base +  0], v.x);
        atomicAdd(&st[2 * 200 + base +  1], v.y);
        atomicAdd(&st[2 * 200 + base + 20], v.z);
        atomicAdd(&st[2 * 200 + base + 21], v.w);
        v = make_float4(acc.x - s3.x, acc.y - s3.y, acc.z - s3.z, acc.w - s3.w);
        atomicAdd(&st[3 * 200 + base +  0], v.x);
        atomicAdd(&st[3 * 200 + base +  1], v.y);
        atomicAdd(&st[3 * 200 + base + 20], v.z);
        atomicAdd(&st[3 * 200 + base + 21], v.w);
    }
    __syncthreads();   // barrier 3: st complete

    // ---- phase 3: epilogue, 600 outputs ----
    const float avalid = (n < natom) ? 1.0f : 0.0f;
    float* ob = out + (size_t)bid * 600;
    for (int o = t; o < 600; o += 128) {
        const int l   = o / 200;
        const int rem = o - 200 * l;
        const int c   = rem / 20;
        const int g   = rem - 20 * c;
        const int ab  = d_abase[l];
        const int ac  = d_acnt[l];
        float v = 0.0f;
        if (c < 4) {
            for (int k = 0; k < ac; ++k) {
                const int a = ab + k;
                const float tv = st[c * 200 + a * 20 + g];
                v = fmaf(d_wA[a] * tv, tv, v);
            }
        } else {
            const int p  = c - 4;
            const int pi = d_PI[p];
            const int pj = d_PJ[p];
            for (int k = 0; k < ac; ++k) {
                const int a = ab + k;
                const float ti = st[pi * 200 + a * 20 + g];
                const float tj = st[pj * 200 + a * 20 + g];
                v = fmaf(2.0f * d_wA[a] * ti, tj, v);
            }
        }
        ob[o] = v * avalid;
    }
}

extern "C" void kernel_launch(void* const* d_in, const int* in_sizes, int n_in,
                              void* d_out, int out_size, void* d_ws, size_t ws_size,
                              hipStream_t stream) {
    (void)n_in; (void)out_size; (void)d_ws; (void)ws_size;
    const float* coords  = (const float*)d_in[0];
    const int*   charges = (const int*)d_in[1];
    const int*   natoms  = (const int*)d_in[2];
    float* out = (float*)d_out;
    const int B = in_sizes[2];
    egto_kernel<<<dim3(B * NATOM), dim3(128), 0, stream>>>(coords, charges, natoms, out);
}

// Round 5
// 83.285 us; speedup vs baseline: 1.3110x; 1.3110x over previous
//
#include <hip/hip_runtime.h>

// ElementalGTO fingerprint kernel for MI355X (gfx950), round 5 — MFMA.
// B=32, N=128, 4 species, 20 gaussians, LMAX=2 -> 10 ang comps, FP_SIZE=600.
//
// Pair channels are cross terms: fpp[p] = sum_a 2*w_a*t[pi][a][g]*t[pj][a][g],
// so only per-species t[s][a][g] is accumulated.
//
// R5: the contraction t[a][s,g] = sum_m angT[a][m]*radT[g][m] (m in species
// segment s) is done with v_mfma_f32_16x16x32_bf16 instead of scalar FMAs.
// Neighbors are species-sorted into slots with 32-ALIGNED segment bases
// (worst-case padded K = 224 <= 232-slot rows); tables are written directly
// in MFMA operand layout (angT[16 rows][232], radT[32 rows][232], bf16,
// zero-filled first so segment pads / unused rows contribute exact zeros).
// Wave 0 computes D columns 0-15 (g=0..15), wave 1 columns 16-19.
// This attacks the measured bottleneck: VALU instruction issue (R1-R4 burned
// ~2000 instrs/wave on scalar FMAs + LDS scalar reads; MFMA path needs ~8
// MFMA + ~16 b128 frag reads per wave).

#define NATOM 128
#define PITCH_H 232          // shorts per table row (224 slots + pad)

using short8 = __attribute__((ext_vector_type(8))) short;
using f32x4  = __attribute__((ext_vector_type(4))) float;

__device__ const float d_wA[10]   = {1.f,1.f,1.f,1.f,1.f,2.f,1.f,2.f,2.f,1.f};
__device__ const int   d_abase[3] = {0, 1, 4};
__device__ const int   d_acnt[3]  = {1, 3, 6};
__device__ const int   d_PI[6]    = {0,0,0,1,1,2};
__device__ const int   d_PJ[6]    = {1,2,3,2,3,3};

__device__ __forceinline__ short pack_bf16(float x) {
    return (short)((__float_as_uint(x) + 0x8000u) >> 16);
}

__global__ __launch_bounds__(128)
void egto_kernel(const float* __restrict__ coords,
                 const int*   __restrict__ charges,
                 const int*   __restrict__ natoms,
                 float*       __restrict__ out)
{
    __shared__ __align__(16) short s_ang[16 * PITCH_H];   // A: [a(row)][slot] bf16
    __shared__ __align__(16) short s_rad[32 * PITCH_H];   // B^T: [g(row)][slot] bf16
    __shared__ __align__(16) float s_t[4 * 24 * 20];      // t: [s][g(col,24 pitch)][a]
    __shared__ int s_wcnt[2][4];

    const int bid  = blockIdx.x;
    const int b    = bid >> 7;
    const int n    = bid & 127;
    const int t    = threadIdx.x;
    const int wid  = t >> 6;
    const int lane = t & 63;

    const float* cb = coords + (size_t)b * NATOM * 3;
    const float cx = cb[t * 3 + 0];
    const float cy = cb[t * 3 + 1];
    const float cz = cb[t * 3 + 2];
    const float xn = cb[n * 3 + 0];     // block-uniform -> scalar loads
    const float yn = cb[n * 3 + 1];
    const float zn = cb[n * 3 + 2];
    const int ch = charges[b * NATOM + t];
    const int sp = (ch == 1) ? 0 : (ch == 6) ? 1 : (ch == 7) ? 2 : 3;
    const int natom = natoms[b];

    const float dx = xn - cx;
    const float dy = yn - cy;
    const float dz = zn - cz;
    const float d2 = dx * dx + dy * dy + dz * dz;
    const bool  valid = (d2 < 36.0f) && (t != n) && (t < natom);

    // ---- per-wave species ranking (valid threads only) ----
    const unsigned long long m0 = __ballot(valid && sp == 0);
    const unsigned long long m1 = __ballot(valid && sp == 1);
    const unsigned long long m2 = __ballot(valid && sp == 2);
    const unsigned long long m3 = __ballot(valid && sp == 3);
    const unsigned long long below = (1ull << lane) - 1ull;
    const unsigned long long msel = (sp == 0) ? m0 : (sp == 1) ? m1 : (sp == 2) ? m2 : m3;
    const int rank = __popcll(msel & below);
    if (lane == 0) {
        s_wcnt[wid][0] = __popcll(m0);
        s_wcnt[wid][1] = __popcll(m1);
        s_wcnt[wid][2] = __popcll(m2);
        s_wcnt[wid][3] = __popcll(m3);
    }

    // ---- zero-fill tables (pads / unused rows must be exact zeros) ----
    {
        uint4 z = make_uint4(0u, 0u, 0u, 0u);
        uint4* pa = reinterpret_cast<uint4*>(s_ang);
        uint4* pr = reinterpret_cast<uint4*>(s_rad);
        for (int i = t; i < 16 * PITCH_H / 8; i += 128) pa[i] = z;
        for (int i = t; i < 32 * PITCH_H / 8; i += 128) pr[i] = z;
    }
    __syncthreads();   // barrier 1: wcnt + zeros visible

    const int c0 = s_wcnt[0][0] + s_wcnt[1][0];
    const int c1 = s_wcnt[0][1] + s_wcnt[1][1];
    const int c2 = s_wcnt[0][2] + s_wcnt[1][2];
    const int c3 = s_wcnt[0][3] + s_wcnt[1][3];
    const int k0 = (c0 + 31) >> 5, k1 = (c1 + 31) >> 5;
    const int k2 = (c2 + 31) >> 5, k3 = (c3 + 31) >> 5;
    // 32-aligned segment bases (in slots)
    const int S0 = 0, S1 = k0 << 5, S2 = (k0 + k1) << 5, S3 = (k0 + k1 + k2) << 5;

    // ---- phase 1: tables, written transposed into MFMA layout ----
    if (valid) {
        const int segb = (sp == 0) ? S0 : (sp == 1) ? S1 : (sp == 2) ? S2 : S3;
        const int slot = segb + (wid ? s_wcnt[0][sp] : 0) + rank;
        const float dist = sqrtf(d2);
        const float cutoff = 0.5f * (__cosf(dist * 0.52359877559829887f) + 1.0f);
        const float cm = 0.79788456080286536f * cutoff;   // sqrt(2/pi)*cutoff
        const float invd = 1.0f / dist;
        const float i2 = invd * invd;
        const float i3 = i2 * invd;
        const float i4 = i2 * i2;
        short* ap = s_ang + slot;
        ap[0 * PITCH_H] = pack_bf16(i2);
        ap[1 * PITCH_H] = pack_bf16(i3 * dx);
        ap[2 * PITCH_H] = pack_bf16(i3 * dy);
        ap[3 * PITCH_H] = pack_bf16(i3 * dz);
        ap[4 * PITCH_H] = pack_bf16(i4 * dx * dx);
        ap[5 * PITCH_H] = pack_bf16(i4 * dx * dy);
        ap[6 * PITCH_H] = pack_bf16(i4 * dy * dy);
        ap[7 * PITCH_H] = pack_bf16(i4 * dx * dz);
        ap[8 * PITCH_H] = pack_bf16(i4 * dy * dz);
        ap[9 * PITCH_H] = pack_bf16(i4 * dz * dz);
        // radial gaussians by geometric recurrence:
        // rad_g = cm*exp(-2*u_g^2), u_g = dist-0.3(g+1)
        // rad_{g+1} = rad_g * exp(1.2*u_g - 0.18); ratio *= exp(-0.36)
        const float u0 = dist - 0.3f;
        float val   = cm * __expf(-2.0f * u0 * u0);
        float ratio = __expf(1.2f * u0 - 0.18f);
        const float cmul = 0.697676326071031f;            // exp(-0.36)
        short* rp = s_rad + slot;
#pragma unroll
        for (int g = 0; g < 20; ++g) {
            rp[g * PITCH_H] = pack_bf16(val);
            val *= ratio; ratio *= cmul;
        }
    }
    __syncthreads();   // barrier 2: tables ready

    // ---- phase 2: MFMA contraction, per-species accumulators ----
    {
        const int q   = lane >> 4;         // k-octet selector
        const int r16 = lane & 15;
        const short* aP = s_ang + r16 * PITCH_H + q * 8;               // A row = a
        const short* bP = s_rad + (wid * 16 + r16) * PITCH_H + q * 8;  // B row = g
        const int col = wid * 16 + r16;    // global g column this lane produces
        const int ks[4]   = {k0, k1, k2, k3};
        const int base[4] = {S0, S1, S2, S3};
#pragma unroll
        for (int s = 0; s < 4; ++s) {
            f32x4 acc = {0.f, 0.f, 0.f, 0.f};
            const int nk = ks[s];
            const int kb = base[s];
            for (int kk = 0; kk < nk; ++kk) {
                const short8 af = *reinterpret_cast<const short8*>(aP + kb + kk * 32);
                const short8 bf = *reinterpret_cast<const short8*>(bP + kb + kk * 32);
                acc = __builtin_amdgcn_mfma_f32_16x16x32_bf16(af, bf, acc, 0, 0, 0);
            }
            // D: col=lane&15 (g), rows = q*4 + reg (a); write b128
            if (col < 20) {
                *reinterpret_cast<f32x4*>(&s_t[(s * 24 + col) * 20 + q * 4]) = acc;
            }
        }
    }
    __syncthreads();   // barrier 3: s_t complete

    // ---- phase 3: epilogue, 600 outputs ----
    const float avalid = (n < natom) ? 1.0f : 0.0f;
    float* ob = out + (size_t)bid * 600;
    for (int o = t; o < 600; o += 128) {
        const int l   = o / 200;
        const int rem = o - 200 * l;
        const int c   = rem / 20;
        const int g   = rem - 20 * c;
        const int ab  = d_abase[l];
        const int ac  = d_acnt[l];
        float v = 0.0f;
        if (c < 4) {
            const float* tc = &s_t[(c * 24 + g) * 20];
            for (int k = 0; k < ac; ++k) {
                const int a = ab + k;
                const float tv = tc[a];
                v = fmaf(d_wA[a] * tv, tv, v);
            }
        } else {
            const int p  = c - 4;
            const float* ti = &s_t[(d_PI[p] * 24 + g) * 20];
            const float* tj = &s_t[(d_PJ[p] * 24 + g) * 20];
            for (int k = 0; k < ac; ++k) {
                const int a = ab + k;
                v = fmaf(2.0f * d_wA[a] * ti[a], tj[a], v);
            }
        }
        ob[o] = v * avalid;
    }
}

extern "C" void kernel_launch(void* const* d_in, const int* in_sizes, int n_in,
                              void* d_out, int out_size, void* d_ws, size_t ws_size,
                              hipStream_t stream) {
    (void)n_in; (void)out_size; (void)d_ws; (void)ws_size;
    const float* coords  = (const float*)d_in[0];
    const int*   charges = (const int*)d_in[1];
    const int*   natoms  = (const int*)d_in[2];
    float* out = (float*)d_out;
    const int B = in_sizes[2];
    egto_kernel<<<dim3(B * NATOM), dim3(128), 0, stream>>>(coords, charges, natoms, out);
}

// Round 6
// 76.527 us; speedup vs baseline: 1.4267x; 1.0883x over previous
//
#include <hip/hip_runtime.h>

// ElementalGTO fingerprint kernel for MI355X (gfx950), round 6.
// B=32, N=128, 4 species, 20 gaussians, LMAX=2 -> 10 ang comps, FP_SIZE=600.
//
// Pair channels are cross terms: fpp[p] = sum_a 2*w_a*t[pi][a][g]*t[pj][a][g],
// so only per-species t[s][a][g] is accumulated. Contraction via
// v_mfma_f32_16x16x32_bf16 over species-segmented, 32-aligned K slots.
//
// R6 (occupancy + latency): A table stores only rows 0-9 (MFMA A-row i feeds
// only D-row i; D rows 10-15 discarded -> lanes r16>=10 clamp to row 9).
// B table stores only rows 0-19 (cols >=20 discarded -> clamp to row 19).
// s_t pitch 24->20. LDS 30 KB -> 19.9 KB => 8 blocks/CU (16 waves/CU).
// Radial gaussians: 20 independent __expf (no serial recurrence chain).

#define NATOM 128
#define PITCH_H 232          // shorts per table row (224 max used slots + pad)

using short8 = __attribute__((ext_vector_type(8))) short;
using f32x4  = __attribute__((ext_vector_type(4))) float;

__device__ const float d_wA[10]   = {1.f,1.f,1.f,1.f,1.f,2.f,1.f,2.f,2.f,1.f};
__device__ const int   d_abase[3] = {0, 1, 4};
__device__ const int   d_acnt[3]  = {1, 3, 6};
__device__ const int   d_PI[6]    = {0,0,0,1,1,2};
__device__ const int   d_PJ[6]    = {1,2,3,2,3,3};

__device__ __forceinline__ short pack_bf16(float x) {
    return (short)((__float_as_uint(x) + 0x8000u) >> 16);
}

__global__ __launch_bounds__(128)
void egto_kernel(const float* __restrict__ coords,
                 const int*   __restrict__ charges,
                 const int*   __restrict__ natoms,
                 float*       __restrict__ out)
{
    __shared__ __align__(16) short s_ang[10 * PITCH_H];   // A: [a(0..9)][slot] bf16
    __shared__ __align__(16) short s_rad[20 * PITCH_H];   // B^T: [g(0..19)][slot] bf16
    __shared__ __align__(16) float s_t[4 * 20 * 20];      // t: [s][g][a] fp32
    __shared__ int s_wcnt[2][4];

    const int bid  = blockIdx.x;
    const int b    = bid >> 7;
    const int n    = bid & 127;
    const int t    = threadIdx.x;
    const int wid  = t >> 6;
    const int lane = t & 63;

    const float* cb = coords + (size_t)b * NATOM * 3;
    const float cx = cb[t * 3 + 0];
    const float cy = cb[t * 3 + 1];
    const float cz = cb[t * 3 + 2];
    const float xn = cb[n * 3 + 0];     // block-uniform -> scalar loads
    const float yn = cb[n * 3 + 1];
    const float zn = cb[n * 3 + 2];
    const int ch = charges[b * NATOM + t];
    const int sp = (ch == 1) ? 0 : (ch == 6) ? 1 : (ch == 7) ? 2 : 3;
    const int natom = natoms[b];

    const float dx = xn - cx;
    const float dy = yn - cy;
    const float dz = zn - cz;
    const float d2 = dx * dx + dy * dy + dz * dz;
    const bool  valid = (d2 < 36.0f) && (t != n) && (t < natom);

    // ---- per-wave species ranking (valid threads only) ----
    const unsigned long long m0 = __ballot(valid && sp == 0);
    const unsigned long long m1 = __ballot(valid && sp == 1);
    const unsigned long long m2 = __ballot(valid && sp == 2);
    const unsigned long long m3 = __ballot(valid && sp == 3);
    const unsigned long long below = (1ull << lane) - 1ull;
    const unsigned long long msel = (sp == 0) ? m0 : (sp == 1) ? m1 : (sp == 2) ? m2 : m3;
    const int rank = __popcll(msel & below);
    if (lane == 0) {
        s_wcnt[wid][0] = __popcll(m0);
        s_wcnt[wid][1] = __popcll(m1);
        s_wcnt[wid][2] = __popcll(m2);
        s_wcnt[wid][3] = __popcll(m3);
    }

    // ---- zero-fill tables (segment pad slots must contribute exact zeros;
    //      garbage could be an Inf/NaN bit pattern -> 0*Inf = NaN) ----
    {
        uint4 z = make_uint4(0u, 0u, 0u, 0u);
        uint4* pa = reinterpret_cast<uint4*>(s_ang);
        uint4* pr = reinterpret_cast<uint4*>(s_rad);
        for (int i = t; i < 10 * PITCH_H / 8; i += 128) pa[i] = z;
        for (int i = t; i < 20 * PITCH_H / 8; i += 128) pr[i] = z;
    }
    __syncthreads();   // barrier 1: wcnt + zeros visible

    const int c0 = s_wcnt[0][0] + s_wcnt[1][0];
    const int c1 = s_wcnt[0][1] + s_wcnt[1][1];
    const int c2 = s_wcnt[0][2] + s_wcnt[1][2];
    const int c3 = s_wcnt[0][3] + s_wcnt[1][3];
    const int k0 = (c0 + 31) >> 5, k1 = (c1 + 31) >> 5;
    const int k2 = (c2 + 31) >> 5, k3 = (c3 + 31) >> 5;
    // 32-aligned segment bases (in slots); S3 + 32*k3 <= 224
    const int S0 = 0, S1 = k0 << 5, S2 = (k0 + k1) << 5, S3 = (k0 + k1 + k2) << 5;

    // ---- phase 1: tables, written transposed into MFMA layout ----
    if (valid) {
        const int segb = (sp == 0) ? S0 : (sp == 1) ? S1 : (sp == 2) ? S2 : S3;
        const int slot = segb + (wid ? s_wcnt[0][sp] : 0) + rank;
        const float dist = sqrtf(d2);
        const float cutoff = 0.5f * (__cosf(dist * 0.52359877559829887f) + 1.0f);
        const float cm = 0.79788456080286536f * cutoff;   // sqrt(2/pi)*cutoff
        const float invd = 1.0f / dist;
        const float i2 = invd * invd;
        const float i3 = i2 * invd;
        const float i4 = i2 * i2;
        short* ap = s_ang + slot;
        ap[0 * PITCH_H] = pack_bf16(i2);
        ap[1 * PITCH_H] = pack_bf16(i3 * dx);
        ap[2 * PITCH_H] = pack_bf16(i3 * dy);
        ap[3 * PITCH_H] = pack_bf16(i3 * dz);
        ap[4 * PITCH_H] = pack_bf16(i4 * dx * dx);
        ap[5 * PITCH_H] = pack_bf16(i4 * dx * dy);
        ap[6 * PITCH_H] = pack_bf16(i4 * dy * dy);
        ap[7 * PITCH_H] = pack_bf16(i4 * dx * dz);
        ap[8 * PITCH_H] = pack_bf16(i4 * dy * dz);
        ap[9 * PITCH_H] = pack_bf16(i4 * dz * dz);
        // radial gaussians: 20 independent exps (no serial chain)
        short* rp = s_rad + slot;
#pragma unroll
        for (int g = 0; g < 20; ++g) {
            const float dd = dist - 0.3f * (float)(g + 1);
            rp[g * PITCH_H] = pack_bf16(cm * __expf(-2.0f * dd * dd));
        }
    }
    __syncthreads();   // barrier 2: tables ready

    // ---- phase 2: MFMA contraction, per-species accumulators ----
    {
        const int q    = lane >> 4;        // k-octet selector
        const int r16  = lane & 15;
        const int aRow = (r16 < 10) ? r16 : 9;               // rows 10-15 discarded
        const int bRow = (wid * 16 + r16 < 20) ? (wid * 16 + r16) : 19;
        const short* aP = s_ang + aRow * PITCH_H + q * 8;
        const short* bP = s_rad + bRow * PITCH_H + q * 8;
        const int col = wid * 16 + r16;    // g column this lane produces
        const int ks[4]   = {k0, k1, k2, k3};
        const int base[4] = {S0, S1, S2, S3};
#pragma unroll
        for (int s = 0; s < 4; ++s) {
            f32x4 acc = {0.f, 0.f, 0.f, 0.f};
            const int nk = ks[s];
            const int kb = base[s];
            for (int kk = 0; kk < nk; ++kk) {
                const short8 af = *reinterpret_cast<const short8*>(aP + kb + kk * 32);
                const short8 bf = *reinterpret_cast<const short8*>(bP + kb + kk * 32);
                acc = __builtin_amdgcn_mfma_f32_16x16x32_bf16(af, bf, acc, 0, 0, 0);
            }
            // D: col=lane&15 (g), rows = q*4 + reg (a)
            if (col < 20) {
                *reinterpret_cast<f32x4*>(&s_t[(s * 20 + col) * 20 + q * 4]) = acc;
            }
        }
    }
    __syncthreads();   // barrier 3: s_t complete

    // ---- phase 3: epilogue, 600 outputs ----
    const float avalid = (n < natom) ? 1.0f : 0.0f;
    float* ob = out + (size_t)bid * 600;
    for (int o = t; o < 600; o += 128) {
        const int l   = o / 200;
        const int rem = o - 200 * l;
        const int c   = rem / 20;
        const int g   = rem - 20 * c;
        const int ab  = d_abase[l];
        const int ac  = d_acnt[l];
        float v = 0.0f;
        if (c < 4) {
            const float* tc = &s_t[(c * 20 + g) * 20];
            for (int k = 0; k < ac; ++k) {
                const int a = ab + k;
                const float tv = tc[a];
                v = fmaf(d_wA[a] * tv, tv, v);
            }
        } else {
            const int p  = c - 4;
            const float* ti = &s_t[(d_PI[p] * 20 + g) * 20];
            const float* tj = &s_t[(d_PJ[p] * 20 + g) * 20];
            for (int k = 0; k < ac; ++k) {
                const int a = ab + k;
                v = fmaf(2.0f * d_wA[a] * ti[a], tj[a], v);
            }
        }
        ob[o] = v * avalid;
    }
}

extern "C" void kernel_launch(void* const* d_in, const int* in_sizes, int n_in,
                              void* d_out, int out_size, void* d_ws, size_t ws_size,
                              hipStream_t stream) {
    (void)n_in; (void)out_size; (void)d_ws; (void)ws_size;
    const float* coords  = (const float*)d_in[0];
    const int*   charges = (const int*)d_in[1];
    const int*   natoms  = (const int*)d_in[2];
    float* out = (float*)d_out;
    const int B = in_sizes[2];
    egto_kernel<<<dim3(B * NATOM), dim3(128), 0, stream>>>(coords, charges, natoms, out);
}

// Round 7
// 67.828 us; speedup vs baseline: 1.6097x; 1.1283x over previous
//
#include <hip/hip_runtime.h>

// ElementalGTO fingerprint kernel for MI355X (gfx950), round 7.
// B=32, N=128, 4 species, 20 gaussians, LMAX=2 -> 10 ang comps, FP_SIZE=600.
//
// Pair channels are cross terms: fpp[p] = sum_a 2*w_a*t[pi][a][g]*t[pj][a][g],
// so only per-species t[s][a][g] is accumulated.
//
// R7 (latency attack): single-wave (64-thread) blocks, one (b,n) each; each
// thread builds 2 neighbor tables; species sort fully in registers (ballots);
// barriers are single-wave (no cross-wave coupling). Contraction via ONE
// v_mfma_f32_32x32x16_bf16 chain (D covers all 10 a-rows x 20 g-cols;
// 16-aligned species segments, K <= 176). Epilogue entirely in registers:
// all 4 species of t[a][g] live in the same lane; one __shfl per channel
// merges the high-half (a=4..7) partials. LDS 19.9 KB -> 11.0 KB
// => ~14 independent waves/CU.

#define NATOM 128
#define PITCH_H 184   // shorts per table row: K<=176 + 8 pad; stride 368 B (16B-aligned)

using short8 = __attribute__((ext_vector_type(8))) short;
using f32x16 = __attribute__((ext_vector_type(16))) float;

__device__ __forceinline__ short pack_bf16(float x) {
    return (short)((__float_as_uint(x) + 0x8000u) >> 16);
}

__global__ __launch_bounds__(64, 4)
void egto_kernel(const float* __restrict__ coords,
                 const int*   __restrict__ charges,
                 const int*   __restrict__ natoms,
                 float*       __restrict__ out)
{
    __shared__ __align__(16) short s_ang[10 * PITCH_H];   // A: [a(0..9)][k-slot] bf16
    __shared__ __align__(16) short s_rad[20 * PITCH_H];   // B: [g(0..19)][k-slot] bf16

    const int bid = blockIdx.x;
    const int b   = bid >> 7;
    const int n   = bid & 127;
    const int t   = threadIdx.x;          // lane 0..63

    const float* cb = coords + (size_t)b * NATOM * 3;
    // neighbors t and t+64 (per-lane), atom n (wave-uniform -> scalar loads)
    const float ax0 = cb[t * 3 + 0],        ay0 = cb[t * 3 + 1],        az0 = cb[t * 3 + 2];
    const float ax1 = cb[(t + 64) * 3 + 0], ay1 = cb[(t + 64) * 3 + 1], az1 = cb[(t + 64) * 3 + 2];
    const float xn  = cb[n * 3 + 0],        yn  = cb[n * 3 + 1],        zn  = cb[n * 3 + 2];
    const int ch0 = charges[b * NATOM + t];
    const int ch1 = charges[b * NATOM + t + 64];
    const int natom = natoms[b];
    const int sp0 = (ch0 == 1) ? 0 : (ch0 == 6) ? 1 : (ch0 == 7) ? 2 : 3;
    const int sp1 = (ch1 == 1) ? 0 : (ch1 == 6) ? 1 : (ch1 == 7) ? 2 : 3;

    const float dx0 = xn - ax0, dy0 = yn - ay0, dz0 = zn - az0;
    const float dx1 = xn - ax1, dy1 = yn - ay1, dz1 = zn - az1;
    const float d20 = dx0 * dx0 + dy0 * dy0 + dz0 * dz0;
    const float d21 = dx1 * dx1 + dy1 * dy1 + dz1 * dz1;
    const bool v0 = (d20 < 36.0f) && (t != n) && (t < natom);
    const bool v1 = (d21 < 36.0f) && ((t + 64) != n) && ((t + 64) < natom);

    // ---- in-register species sort (two neighbor sets) ----
    const unsigned long long A0 = __ballot(v0 && sp0 == 0);
    const unsigned long long A1 = __ballot(v0 && sp0 == 1);
    const unsigned long long A2 = __ballot(v0 && sp0 == 2);
    const unsigned long long A3 = __ballot(v0 && sp0 == 3);
    const unsigned long long B0 = __ballot(v1 && sp1 == 0);
    const unsigned long long B1 = __ballot(v1 && sp1 == 1);
    const unsigned long long B2 = __ballot(v1 && sp1 == 2);
    const unsigned long long B3 = __ballot(v1 && sp1 == 3);
    const int cnt0 = __popcll(A0) + __popcll(B0);
    const int cnt1 = __popcll(A1) + __popcll(B1);
    const int cnt2 = __popcll(A2) + __popcll(B2);
    const int cnt3 = __popcll(A3) + __popcll(B3);
    const int u0 = (cnt0 + 15) >> 4, u1 = (cnt1 + 15) >> 4;
    const int u2 = (cnt2 + 15) >> 4, u3 = (cnt3 + 15) >> 4;
    const int S0 = 0, S1 = u0 << 4, S2 = (u0 + u1) << 4, S3 = (u0 + u1 + u2) << 4;

    const unsigned long long below = (1ull << t) - 1ull;
    const unsigned long long mA0 = (sp0 == 0) ? A0 : (sp0 == 1) ? A1 : (sp0 == 2) ? A2 : A3;
    const int seg0 = (sp0 == 0) ? S0 : (sp0 == 1) ? S1 : (sp0 == 2) ? S2 : S3;
    const int slot0 = seg0 + __popcll(mA0 & below);
    const unsigned long long mA1 = (sp1 == 0) ? A0 : (sp1 == 1) ? A1 : (sp1 == 2) ? A2 : A3;
    const unsigned long long mB1 = (sp1 == 0) ? B0 : (sp1 == 1) ? B1 : (sp1 == 2) ? B2 : B3;
    const int seg1 = (sp1 == 0) ? S0 : (sp1 == 1) ? S1 : (sp1 == 2) ? S2 : S3;
    const int slot1 = seg1 + __popcll(mA1) + __popcll(mB1 & below);

    // ---- zero-fill tables (pad slots must multiply as exact zeros) ----
    {
        const uint4 z = make_uint4(0u, 0u, 0u, 0u);
        uint4* pa = reinterpret_cast<uint4*>(s_ang);   // 230 uint4
        uint4* pr = reinterpret_cast<uint4*>(s_rad);   // 460 uint4
        for (int i = t; i < 230; i += 64) pa[i] = z;
        for (int i = t; i < 460; i += 64) pr[i] = z;
    }
    __syncthreads();   // single-wave barrier (cheap): zeros before table writes

    // ---- phase 1: per-neighbor tables in MFMA operand layout ----
    auto emit = [&](bool v, int slot, float dx, float dy, float dz, float d2) {
        if (!v) return;
        const float dist = sqrtf(d2);
        const float cm = 0.79788456080286536f *
                         (0.5f * (__cosf(dist * 0.52359877559829887f) + 1.0f));
        const float invd = 1.0f / dist;
        const float i2 = invd * invd;
        const float i3 = i2 * invd;
        const float i4 = i2 * i2;
        short* ap = s_ang + slot;
        ap[0 * PITCH_H] = pack_bf16(i2);
        ap[1 * PITCH_H] = pack_bf16(i3 * dx);
        ap[2 * PITCH_H] = pack_bf16(i3 * dy);
        ap[3 * PITCH_H] = pack_bf16(i3 * dz);
        ap[4 * PITCH_H] = pack_bf16(i4 * dx * dx);
        ap[5 * PITCH_H] = pack_bf16(i4 * dx * dy);
        ap[6 * PITCH_H] = pack_bf16(i4 * dy * dy);
        ap[7 * PITCH_H] = pack_bf16(i4 * dx * dz);
        ap[8 * PITCH_H] = pack_bf16(i4 * dy * dz);
        ap[9 * PITCH_H] = pack_bf16(i4 * dz * dz);
        short* rp = s_rad + slot;
#pragma unroll
        for (int g = 0; g < 20; ++g) {
            const float dd = dist - 0.3f * (float)(g + 1);
            rp[g * PITCH_H] = pack_bf16(cm * __expf(-2.0f * dd * dd));
        }
    };
    emit(v0, slot0, dx0, dy0, dz0, d20);
    emit(v1, slot1, dx1, dy1, dz1, d21);
    __syncthreads();   // single-wave barrier: tables ready

    // ---- phase 2: one 32x32x16 MFMA chain per species segment ----
    // A: lane holds row m=lane&31 (clamp to 9), k = 8*(lane>>5)+j
    // B: lane holds col g=lane&31 (clamp to 19), same k
    // D: col = lane&31, row = (reg&3) + 8*(reg>>2) + 4*(lane>>5)
    const int r32 = t & 31;
    const int h   = t >> 5;
    const short* aP = s_ang + ((r32 < 10) ? r32 : 9)  * PITCH_H + h * 8;
    const short* bP = s_rad + ((r32 < 20) ? r32 : 19) * PITCH_H + h * 8;
    f32x16 acc[4];
    const int Sarr[4] = {S0, S1, S2, S3};
    const int uarr[4] = {u0, u1, u2, u3};
#pragma unroll
    for (int s = 0; s < 4; ++s) {
        f32x16 a = {0.f, 0.f, 0.f, 0.f, 0.f, 0.f, 0.f, 0.f,
                    0.f, 0.f, 0.f, 0.f, 0.f, 0.f, 0.f, 0.f};
        const int kb = Sarr[s];
        const int nk = uarr[s];
        for (int kk = 0; kk < nk; ++kk) {
            const short8 af = *reinterpret_cast<const short8*>(aP + kb + kk * 16);
            const short8 bf = *reinterpret_cast<const short8*>(bP + kb + kk * 16);
            a = __builtin_amdgcn_mfma_f32_32x32x16_bf16(af, bf, a, 0, 0, 0);
        }
        acc[s] = a;
    }

    // ---- phase 3: register epilogue ----
    // Relevant D regs: half0 (h=0): reg0-3 -> a=0..3, reg4 -> a=8, reg5 -> a=9;
    //                  half1 (h=1): reg0-3 -> a=4..7.
    // w_a = {1,1,1,1, 1,2,1,2, 2,1}; l(a): a=0 -> l0; a=1..3 -> l1; a=4..9 -> l2.
    float T[4][6];
#pragma unroll
    for (int s = 0; s < 4; ++s)
#pragma unroll
        for (int r = 0; r < 6; ++r) T[s][r] = acc[s][r];

    const float W0 = h ? 1.f : 0.f;   // a=4
    const float W1 = h ? 2.f : 0.f;   // a=5
    const float W2 = h ? 1.f : 0.f;   // a=6
    const float W3 = h ? 2.f : 0.f;   // a=7
    const float W4 = h ? 0.f : 2.f;   // a=8
    const float W5 = h ? 0.f : 1.f;   // a=9
    const int   src    = r32 + 32;    // shfl source: high-half lane of same col
    const bool  writer = (h == 0) && (r32 < 20);
    const float avalid = (n < natom) ? 1.0f : 0.0f;
    float* ob = out + (size_t)bid * 600 + r32;   // + g

    auto channel = [&](const float* ti, const float* tj, float f, int c) {
        const float pr0 = ti[0] * tj[0];
        const float pr1 = ti[1] * tj[1];
        const float pr2 = ti[2] * tj[2];
        const float pr3 = ti[3] * tj[3];
        const float pr4 = ti[4] * tj[4];
        const float pr5 = ti[5] * tj[5];
        const float p0 = pr0;                     // valid in half0 lanes
        const float p1 = pr1 + pr2 + pr3;         // valid in half0 lanes
        float p2 = W0 * pr0 + W1 * pr1 + W2 * pr2 + W3 * pr3 + W4 * pr4 + W5 * pr5;
        p2 += __shfl(p2, src);                    // all lanes participate
        if (writer) {
            ob[c * 20 +   0] = f * p0 * avalid;
            ob[c * 20 + 200] = f * p1 * avalid;
            ob[c * 20 + 400] = f * p2 * avalid;
        }
    };
    channel(T[0], T[0], 1.f, 0);
    channel(T[1], T[1], 1.f, 1);
    channel(T[2], T[2], 1.f, 2);
    channel(T[3], T[3], 1.f, 3);
    channel(T[0], T[1], 2.f, 4);
    channel(T[0], T[2], 2.f, 5);
    channel(T[0], T[3], 2.f, 6);
    channel(T[1], T[2], 2.f, 7);
    channel(T[1], T[3], 2.f, 8);
    channel(T[2], T[3], 2.f, 9);
}

extern "C" void kernel_launch(void* const* d_in, const int* in_sizes, int n_in,
                              void* d_out, int out_size, void* d_ws, size_t ws_size,
                              hipStream_t stream) {
    (void)n_in; (void)out_size; (void)d_ws; (void)ws_size;
    const float* coords  = (const float*)d_in[0];
    const int*   charges = (const int*)d_in[1];
    const int*   natoms  = (const int*)d_in[2];
    float* out = (float*)d_out;
    const int B = in_sizes[2];
    egto_kernel<<<dim3(B * NATOM), dim3(64), 0, stream>>>(coords, charges, natoms, out);
}

// Round 8
// 67.052 us; speedup vs baseline: 1.6283x; 1.0116x over previous
//
#include <hip/hip_runtime.h>

// ElementalGTO fingerprint kernel for MI355X (gfx950), round 8.
// B=32, N=128, 4 species, 20 gaussians, LMAX=2 -> 10 ang comps, FP_SIZE=600.
//
// Pair channels are cross terms: fpp[p] = sum_a 2*w_a*t[pi][a][g]*t[pj][a][g],
// so only per-species t[s][a][g] is accumulated.
//
// R8 (stall attack on the R7 single-wave structure):
//  - K-loop software prefetch: frags for step kk+1 load before MFMA kk issues,
//    breaking the ds_read_b128 -> waitcnt -> mfma serialization of the
//    dynamic-trip species segments.
//  - Radial table: 5 exps (4 anchors + 1 ratio) + exact geometric recurrence
//    (ratio_{g+1} = ratio_g * e^-0.36) in 4 independent 4-step chains --
//    cuts quarter-rate trans-pipe ops per wave ~4x.
//  - float3 coordinate loads (global_load_dwordx3).

#define NATOM 128
#define PITCH_H 184   // shorts per table row: K<=176 + 8 pad; 368 B stride (16B-aligned)

using short8 = __attribute__((ext_vector_type(8))) short;
using f32x16 = __attribute__((ext_vector_type(16))) float;

__device__ __forceinline__ short pack_bf16(float x) {
    return (short)((__float_as_uint(x) + 0x8000u) >> 16);
}

__global__ __launch_bounds__(64, 4)
void egto_kernel(const float* __restrict__ coords,
                 const int*   __restrict__ charges,
                 const int*   __restrict__ natoms,
                 float*       __restrict__ out)
{
    __shared__ __align__(16) short s_ang[10 * PITCH_H];   // A: [a(0..9)][k-slot] bf16
    __shared__ __align__(16) short s_rad[20 * PITCH_H];   // B: [g(0..19)][k-slot] bf16

    const int bid = blockIdx.x;
    const int b   = bid >> 7;
    const int n   = bid & 127;
    const int t   = threadIdx.x;          // lane 0..63

    const float* cb = coords + (size_t)b * NATOM * 3;
    const float3 p0 = *reinterpret_cast<const float3*>(&cb[t * 3]);
    const float3 p1 = *reinterpret_cast<const float3*>(&cb[(t + 64) * 3]);
    const float xn  = cb[n * 3 + 0];      // wave-uniform -> scalar loads
    const float yn  = cb[n * 3 + 1];
    const float zn  = cb[n * 3 + 2];
    const int ch0 = charges[b * NATOM + t];
    const int ch1 = charges[b * NATOM + t + 64];
    const int natom = natoms[b];
    const int sp0 = (ch0 == 1) ? 0 : (ch0 == 6) ? 1 : (ch0 == 7) ? 2 : 3;
    const int sp1 = (ch1 == 1) ? 0 : (ch1 == 6) ? 1 : (ch1 == 7) ? 2 : 3;

    const float dx0 = xn - p0.x, dy0 = yn - p0.y, dz0 = zn - p0.z;
    const float dx1 = xn - p1.x, dy1 = yn - p1.y, dz1 = zn - p1.z;
    const float d20 = dx0 * dx0 + dy0 * dy0 + dz0 * dz0;
    const float d21 = dx1 * dx1 + dy1 * dy1 + dz1 * dz1;
    const bool v0 = (d20 < 36.0f) && (t != n) && (t < natom);
    const bool v1 = (d21 < 36.0f) && ((t + 64) != n) && ((t + 64) < natom);

    // ---- in-register species sort (two neighbor sets) ----
    const unsigned long long A0 = __ballot(v0 && sp0 == 0);
    const unsigned long long A1 = __ballot(v0 && sp0 == 1);
    const unsigned long long A2 = __ballot(v0 && sp0 == 2);
    const unsigned long long A3 = __ballot(v0 && sp0 == 3);
    const unsigned long long B0 = __ballot(v1 && sp1 == 0);
    const unsigned long long B1 = __ballot(v1 && sp1 == 1);
    const unsigned long long B2 = __ballot(v1 && sp1 == 2);
    const unsigned long long B3 = __ballot(v1 && sp1 == 3);
    const int cnt0 = __popcll(A0) + __popcll(B0);
    const int cnt1 = __popcll(A1) + __popcll(B1);
    const int cnt2 = __popcll(A2) + __popcll(B2);
    const int cnt3 = __popcll(A3) + __popcll(B3);
    const int u0 = (cnt0 + 15) >> 4, u1 = (cnt1 + 15) >> 4;
    const int u2 = (cnt2 + 15) >> 4, u3 = (cnt3 + 15) >> 4;
    const int S0 = 0, S1 = u0 << 4, S2 = (u0 + u1) << 4, S3 = (u0 + u1 + u2) << 4;

    const unsigned long long below = (1ull << t) - 1ull;
    const unsigned long long mA0 = (sp0 == 0) ? A0 : (sp0 == 1) ? A1 : (sp0 == 2) ? A2 : A3;
    const int seg0 = (sp0 == 0) ? S0 : (sp0 == 1) ? S1 : (sp0 == 2) ? S2 : S3;
    const int slot0 = seg0 + __popcll(mA0 & below);
    const unsigned long long mA1 = (sp1 == 0) ? A0 : (sp1 == 1) ? A1 : (sp1 == 2) ? A2 : A3;
    const unsigned long long mB1 = (sp1 == 0) ? B0 : (sp1 == 1) ? B1 : (sp1 == 2) ? B2 : B3;
    const int seg1 = (sp1 == 0) ? S0 : (sp1 == 1) ? S1 : (sp1 == 2) ? S2 : S3;
    const int slot1 = seg1 + __popcll(mA1) + __popcll(mB1 & below);

    // ---- zero-fill tables (pad slots must multiply as exact zeros) ----
    {
        const uint4 z = make_uint4(0u, 0u, 0u, 0u);
        uint4* pa = reinterpret_cast<uint4*>(s_ang);   // 230 uint4
        uint4* pr = reinterpret_cast<uint4*>(s_rad);   // 460 uint4
        for (int i = t; i < 230; i += 64) pa[i] = z;
        for (int i = t; i < 460; i += 64) pr[i] = z;
    }
    __syncthreads();   // single-wave barrier: zeros before table writes

    // ---- phase 1: per-neighbor tables in MFMA operand layout ----
    auto emit = [&](bool v, int slot, float dx, float dy, float dz, float d2) {
        if (!v) return;
        const float dist = sqrtf(d2);
        const float cm = 0.79788456080286536f *
                         (0.5f * (__cosf(dist * 0.52359877559829887f) + 1.0f));
        const float invd = 1.0f / dist;
        const float i2 = invd * invd;
        const float i3 = i2 * invd;
        const float i4 = i2 * i2;
        short* ap = s_ang + slot;
        ap[0 * PITCH_H] = pack_bf16(i2);
        ap[1 * PITCH_H] = pack_bf16(i3 * dx);
        ap[2 * PITCH_H] = pack_bf16(i3 * dy);
        ap[3 * PITCH_H] = pack_bf16(i3 * dz);
        ap[4 * PITCH_H] = pack_bf16(i4 * dx * dx);
        ap[5 * PITCH_H] = pack_bf16(i4 * dx * dy);
        ap[6 * PITCH_H] = pack_bf16(i4 * dy * dy);
        ap[7 * PITCH_H] = pack_bf16(i4 * dx * dz);
        ap[8 * PITCH_H] = pack_bf16(i4 * dy * dz);
        ap[9 * PITCH_H] = pack_bf16(i4 * dz * dz);
        // radial: rad_g = cm*exp(-2*u_g^2), u_g = dist-0.3(g+1).
        // ratio_g = rad_{g+1}/rad_g = exp(1.2*u_g - 0.18); ratio_{g+1}=ratio_g*e^-0.36.
        // 4 anchors (g=0,5,10,15) + 1 ratio exp; 4 independent 4-step chains.
        const float ua0 = dist - 0.3f;
        const float ua1 = dist - 1.8f;
        const float ua2 = dist - 3.3f;
        const float ua3 = dist - 4.8f;
        float e0 = cm * __expf(-2.0f * ua0 * ua0);
        float e1 = cm * __expf(-2.0f * ua1 * ua1);
        float e2 = cm * __expf(-2.0f * ua2 * ua2);
        float e3 = cm * __expf(-2.0f * ua3 * ua3);
        float r0 = __expf(1.2f * ua0 - 0.18f);
        float r1 = r0 * 0.16529888822158656f;     // e^-1.8
        float r2 = r0 * 0.02732372244729256f;     // e^-3.6
        float r3 = r0 * 0.0045165809426126675f;   // e^-5.4
        const float cmul = 0.6976763260710304f;   // e^-0.36
        short* rp = s_rad + slot;
#pragma unroll
        for (int j = 0; j < 5; ++j) {
            rp[(j +  0) * PITCH_H] = pack_bf16(e0);
            rp[(j +  5) * PITCH_H] = pack_bf16(e1);
            rp[(j + 10) * PITCH_H] = pack_bf16(e2);
            rp[(j + 15) * PITCH_H] = pack_bf16(e3);
            e0 *= r0; r0 *= cmul;
            e1 *= r1; r1 *= cmul;
            e2 *= r2; r2 *= cmul;
            e3 *= r3; r3 *= cmul;
        }
    };
    emit(v0, slot0, dx0, dy0, dz0, d20);
    emit(v1, slot1, dx1, dy1, dz1, d21);
    __syncthreads();   // single-wave barrier: tables ready

    // ---- phase 2: 32x32x16 MFMA chains with 1-deep frag prefetch ----
    // A: lane holds row m=lane&31 (clamp to 9), k = 8*(lane>>5)+j
    // B: lane holds col g=lane&31 (clamp to 19), same k
    // D: col = lane&31, row = (reg&3) + 8*(reg>>2) + 4*(lane>>5)
    const int r32 = t & 31;
    const int h   = t >> 5;
    const short* aP = s_ang + ((r32 < 10) ? r32 : 9)  * PITCH_H + h * 8;
    const short* bP = s_rad + ((r32 < 20) ? r32 : 19) * PITCH_H + h * 8;
    f32x16 acc[4];
    const int Sarr[4] = {S0, S1, S2, S3};
    const int uarr[4] = {u0, u1, u2, u3};
#pragma unroll
    for (int s = 0; s < 4; ++s) {
        f32x16 a = {0.f, 0.f, 0.f, 0.f, 0.f, 0.f, 0.f, 0.f,
                    0.f, 0.f, 0.f, 0.f, 0.f, 0.f, 0.f, 0.f};
        const int kb = Sarr[s];
        const int nk = uarr[s];
        if (nk > 0) {
            short8 af = *reinterpret_cast<const short8*>(aP + kb);
            short8 bf = *reinterpret_cast<const short8*>(bP + kb);
            for (int kk = 1; kk < nk; ++kk) {
                const short8 af2 = *reinterpret_cast<const short8*>(aP + kb + kk * 16);
                const short8 bf2 = *reinterpret_cast<const short8*>(bP + kb + kk * 16);
                a = __builtin_amdgcn_mfma_f32_32x32x16_bf16(af, bf, a, 0, 0, 0);
                af = af2; bf = bf2;
            }
            a = __builtin_amdgcn_mfma_f32_32x32x16_bf16(af, bf, a, 0, 0, 0);
        }
        acc[s] = a;
    }

    // ---- phase 3: register epilogue ----
    // Relevant D regs: half0 (h=0): reg0-3 -> a=0..3, reg4 -> a=8, reg5 -> a=9;
    //                  half1 (h=1): reg0-3 -> a=4..7.
    // w_a = {1,1,1,1, 1,2,1,2, 2,1}; l(a): a=0 -> l0; a=1..3 -> l1; a=4..9 -> l2.
    float T[4][6];
#pragma unroll
    for (int s = 0; s < 4; ++s)
#pragma unroll
        for (int r = 0; r < 6; ++r) T[s][r] = acc[s][r];

    const float W0 = h ? 1.f : 0.f;   // a=4
    const float W1 = h ? 2.f : 0.f;   // a=5
    const float W2 = h ? 1.f : 0.f;   // a=6
    const float W3 = h ? 2.f : 0.f;   // a=7
    const float W4 = h ? 0.f : 2.f;   // a=8
    const float W5 = h ? 0.f : 1.f;   // a=9
    const int   src    = r32 + 32;    // shfl source: high-half lane of same col
    const bool  writer = (h == 0) && (r32 < 20);
    const float avalid = (n < natom) ? 1.0f : 0.0f;
    float* ob = out + (size_t)bid * 600 + r32;   // + g

    auto channel = [&](const float* ti, const float* tj, float f, int c) {
        const float pr0 = ti[0] * tj[0];
        const float pr1 = ti[1] * tj[1];
        const float pr2 = ti[2] * tj[2];
        const float pr3 = ti[3] * tj[3];
        const float pr4 = ti[4] * tj[4];
        const float pr5 = ti[5] * tj[5];
        const float p0 = pr0;                     // valid in half0 lanes
        const float p1 = pr1 + pr2 + pr3;         // valid in half0 lanes
        float p2 = W0 * pr0 + W1 * pr1 + W2 * pr2 + W3 * pr3 + W4 * pr4 + W5 * pr5;
        p2 += __shfl(p2, src);                    // all lanes participate
        if (writer) {
            ob[c * 20 +   0] = f * p0 * avalid;
            ob[c * 20 + 200] = f * p1 * avalid;
            ob[c * 20 + 400] = f * p2 * avalid;
        }
    };
    channel(T[0], T[0], 1.f, 0);
    channel(T[1], T[1], 1.f, 1);
    channel(T[2], T[2], 1.f, 2);
    channel(T[3], T[3], 1.f, 3);
    channel(T[0], T[1], 2.f, 4);
    channel(T[0], T[2], 2.f, 5);
    channel(T[0], T[3], 2.f, 6);
    channel(T[1], T[2], 2.f, 7);
    channel(T[1], T[3], 2.f, 8);
    channel(T[2], T[3], 2.f, 9);
}

extern "C" void kernel_launch(void* const* d_in, const int* in_sizes, int n_in,
                              void* d_out, int out_size, void* d_ws, size_t ws_size,
                              hipStream_t stream) {
    (void)n_in; (void)out_size; (void)d_ws; (void)ws_size;
    const float* coords  = (const float*)d_in[0];
    const int*   charges = (const int*)d_in[1];
    const int*   natoms  = (const int*)d_in[2];
    float* out = (float*)d_out;
    const int B = in_sizes[2];
    egto_kernel<<<dim3(B * NATOM), dim3(64), 0, stream>>>(coords, charges, natoms, out);
}